// Round 3
// baseline (1131.672 us; speedup 1.0000x reference)
//
#include <hip/hip_runtime.h>

#define DEVFN __device__ __forceinline__

typedef __bf16 bf16x8 __attribute__((ext_vector_type(8)));
typedef float floatx4 __attribute__((ext_vector_type(4)));

// ---------- helpers ----------

DEVFN unsigned short f2bf(float x) {
    union { float f; unsigned u; } v; v.f = x;
    v.u += 0x7FFFu + ((v.u >> 16) & 1u);   // RNE
    return (unsigned short)(v.u >> 16);
}

DEVFN float sigm(float x) { return 1.f / (1.f + __expf(-x)); }
DEVFN float tanh_fast(float x) { float t = __expf(2.f * x); return 1.f - 2.f / (t + 1.f); }

DEVFN void gload_lds16(const unsigned short* g, unsigned short* l) {
    __builtin_amdgcn_global_load_lds(
        (__attribute__((address_space(1))) unsigned int*)g,
        (__attribute__((address_space(3))) unsigned int*)l, 16, 0, 0);
}

// ---------- conversion kernels ----------

// inputs [256,14,1024] f32 -> xt [14,256,1024] bf16
__global__ __launch_bounds__(256) void transpose_bt(const float* __restrict__ in,
                                                    unsigned short* __restrict__ out) {
    int idx = blockIdx.x * 256 + threadIdx.x;
    int k = idx & 1023;
    int row = idx >> 10;                               // t*256 + b
    int t = row >> 8, b = row & 255;
    out[idx] = f2bf(in[(size_t)(b * 14 + t) * 1024 + k]);
}

__global__ __launch_bounds__(256) void f32_to_bf16(const float* __restrict__ in,
                                                   unsigned short* __restrict__ out,
                                                   int n_src, int n_total) {
    int idx = blockIdx.x * 256 + threadIdx.x;
    if (idx < n_total) out[idx] = (idx < n_src) ? f2bf(in[idx]) : (unsigned short)0;
}

// bias (gate-major [4][1024]) -> gate-interleaved float4 [1024][4]
__global__ __launch_bounds__(256) void bias_interleave(const float* __restrict__ a,
                                                       const float* __restrict__ b,
                                                       float* __restrict__ o4, int n) {
    int i = blockIdx.x * 256 + threadIdx.x;
    if (i < n) {
        int g = i >> 10, h = i & 1023;
        o4[h * 4 + g] = a[i] + b[i];
    }
}

// ---------- fused LSTM GEMM ----------
// MODE 0: gates store  -> gout[(m*1024+h)*4 + {i,f,g,o}] = acc + bias4
// MODE 1: LSTM cell    -> c_out, h_out (bf16), pre4/bias4 added to gates
// MODE 2: classifier   -> outp[(b*14+t)*2513 + n] = acc + clsb[n]   (m = t*256+b)
//
// B-tile (MODE 0/1): 128 LDS rows = 4 gates x 32 h-cols gathered so that a
// thread's j-fragments are the 4 gates at one (m,h).  col c=r: gate=(c>>4)&3,
// h = n0 + (c>>6)*16 + (c&15).  MODE 2: plain rows n0+r.
// LDS k-chunks XOR-swizzled via pre-swizzled GLOBAL source (rule 21):
// LDS(row,kq) holds global chunk kq^(row&7); reads apply the same XOR.
template <int BM, int MODE>
__global__ __launch_bounds__(256)
void lstm_fused(const unsigned short* __restrict__ A1, const unsigned short* __restrict__ W1, int k1t,
                const unsigned short* __restrict__ A2, const unsigned short* __restrict__ W2, int k2t,
                const float* __restrict__ pre4,
                const float* __restrict__ bias4,
                const float* __restrict__ c_in,
                float* __restrict__ c_out,
                unsigned short* __restrict__ h_out,
                unsigned short* __restrict__ h_alt, int retire_t,
                float* __restrict__ gout,
                const float* __restrict__ clsb,
                float* __restrict__ outp) {
    constexpr int BK = 64;
    constexpr int FM = BM / 32;                 // m-frags per wave (2x2 wave grid)
    constexpr int AISS = (BM * BK * 2) / 4096;  // staging issues (256 thr x 16B)
    constexpr int BISS = (128 * BK * 2) / 4096;

    __shared__ unsigned short ldsA[BM * BK];
    __shared__ unsigned short ldsB[128 * BK];

    const int tid = threadIdx.x;
    const int m0 = blockIdx.y * BM;
    const int n0 = blockIdx.x * ((MODE == 2) ? 128 : 32);
    const int lane = tid & 63;
    const int wv = tid >> 6;
    const int wm = wv >> 1, wn = wv & 1;
    const int r16 = lane & 15;
    const int kg = lane >> 4;

    floatx4 acc[FM][4];
#pragma unroll
    for (int i = 0; i < FM; ++i)
#pragma unroll
        for (int j = 0; j < 4; ++j) acc[i][j] = {0.f, 0.f, 0.f, 0.f};

    const int ktot = k1t + k2t;
    for (int kt = 0; kt < ktot; ++kt) {
        const unsigned short* As;
        const unsigned short* Ws;
        int ko;
        if (kt < k1t) { As = A1; Ws = W1; ko = kt * BK; }
        else          { As = A2; Ws = W2; ko = (kt - k1t) * BK; }
#pragma unroll
        for (int is = 0; is < AISS; ++is) {
            int c = is * 256 + tid;
            int row = c >> 3, kq = c & 7;
            int kqg = kq ^ (row & 7);           // pre-swizzled source chunk
            gload_lds16(As + (size_t)(m0 + row) * 1024 + ko + kqg * 8, &ldsA[c * 8]);
        }
#pragma unroll
        for (int is = 0; is < BISS; ++is) {
            int c = is * 256 + tid;
            int row = c >> 3, kq = c & 7;
            int kqg = kq ^ (row & 7);
            int wr;
            if (MODE == 2) wr = n0 + row;
            else wr = ((row >> 4) & 3) * 1024 + n0 + ((row >> 6) << 4) + (row & 15);
            gload_lds16(Ws + (size_t)wr * 1024 + ko + kqg * 8, &ldsB[c * 8]);
        }
        __syncthreads();

#pragma unroll
        for (int kk = 0; kk < 2; ++kk) {
            bf16x8 a[FM], b[4];
            const int kqg = kk * 4 + kg;
#pragma unroll
            for (int i = 0; i < FM; ++i) {
                int row = wm * (BM / 2) + i * 16 + r16;
                a[i] = *(const bf16x8*)&ldsA[row * BK + (kqg ^ (row & 7)) * 8];
            }
#pragma unroll
            for (int j = 0; j < 4; ++j) {
                int row = wn * 64 + j * 16 + r16;
                b[j] = *(const bf16x8*)&ldsB[row * BK + (kqg ^ (row & 7)) * 8];
            }
#pragma unroll
            for (int i = 0; i < FM; ++i)
#pragma unroll
                for (int j = 0; j < 4; ++j)
                    acc[i][j] = __builtin_amdgcn_mfma_f32_16x16x32_bf16(a[i], b[j], acc[i][j], 0, 0, 0);
        }
        __syncthreads();
    }

    // ---------- epilogue ----------
    if (MODE == 2) {
#pragma unroll
        for (int i = 0; i < FM; ++i)
#pragma unroll
            for (int j = 0; j < 4; ++j)
#pragma unroll
                for (int rg = 0; rg < 4; ++rg) {
                    int m = m0 + wm * (BM / 2) + i * 16 + kg * 4 + rg;
                    int gn = n0 + wn * 64 + j * 16 + r16;
                    if (gn < 2513) {
                        int bb = m & 255, tt = m >> 8;
                        outp[(size_t)(bb * 14 + tt) * 2513 + gn] = acc[i][j][rg] + clsb[gn];
                    }
                }
        return;
    }

    const int h = n0 + wn * 16 + r16;
    float4 bv = make_float4(0.f, 0.f, 0.f, 0.f);
    if (bias4) bv = *(const float4*)(bias4 + (size_t)h * 4);
    const float4* pre = (const float4*)pre4;
    unsigned short* hw = h_out;
    if (MODE == 1 && (m0 >> 8) == retire_t) hw = h_alt;

#pragma unroll
    for (int i = 0; i < FM; ++i)
#pragma unroll
        for (int rg = 0; rg < 4; ++rg) {
            int m = m0 + wm * (BM / 2) + i * 16 + kg * 4 + rg;
            size_t mh = (size_t)m * 1024 + h;
            float gi_ = acc[i][0][rg] + bv.x;
            float gf_ = acc[i][1][rg] + bv.y;
            float gg_ = acc[i][2][rg] + bv.z;
            float go_ = acc[i][3][rg] + bv.w;
            if (MODE == 0) {
                *(float4*)(gout + mh * 4) = make_float4(gi_, gf_, gg_, go_);
            } else {
                if (pre) {
                    float4 pv = pre[mh];
                    gi_ += pv.x; gf_ += pv.y; gg_ += pv.z; go_ += pv.w;
                }
                float co = c_in ? c_in[mh] : 0.f;
                float iv = sigm(gi_), fv = sigm(gf_);
                float gv = tanh_fast(gg_), ov = sigm(go_);
                float cn = fv * co + iv * gv;
                float hn = ov * tanh_fast(cn);
                c_out[mh] = cn;
                hw[mh] = f2bf(hn);
            }
        }
}

// ---------- launch ----------

extern "C" void kernel_launch(void* const* d_in, const int* in_sizes, int n_in,
                              void* d_out, int out_size, void* d_ws, size_t ws_size,
                              hipStream_t stream) {
    (void)in_sizes; (void)n_in; (void)out_size; (void)ws_size;
    const float* inputs   = (const float*)d_in[0];
    const float* roll_Wih = (const float*)d_in[1];
    const float* roll_Whh = (const float*)d_in[2];
    const float* roll_bih = (const float*)d_in[3];
    const float* roll_bhh = (const float*)d_in[4];
    const float* un_Wih   = (const float*)d_in[5];
    const float* un_Whh   = (const float*)d_in[6];
    const float* un_bih   = (const float*)d_in[7];
    const float* un_bhh   = (const float*)d_in[8];
    const float* cls_Wf   = (const float*)d_in[9];
    const float* cls_b    = (const float*)d_in[10];
    float* out = (float*)d_out;

    char* ws = (char*)d_ws;
    size_t off = 0;
    auto alloc = [&](size_t bytes) -> char* {
        char* p = ws + off;
        off += (bytes + 255) & ~(size_t)255;
        return p;
    };
    unsigned short* xt   = (unsigned short*)alloc(3584ull * 1024 * 2);
    unsigned short* rWih = (unsigned short*)alloc(4096ull * 1024 * 2);
    unsigned short* rWhh = (unsigned short*)alloc(4096ull * 1024 * 2);
    unsigned short* uWih = (unsigned short*)alloc(4096ull * 1024 * 2);
    unsigned short* uWhh = (unsigned short*)alloc(4096ull * 1024 * 2);
    unsigned short* cWp  = (unsigned short*)alloc(2560ull * 1024 * 2);
    float* rbias4 = (float*)alloc(1024 * 4 * 4);
    float* ubias4 = (float*)alloc(1024 * 4 * 4);
    float* Xpre   = (float*)alloc(3584ull * 4096 * 4);   // gate-interleaved [m][h][4]
    float* uc     = (float*)alloc(3584ull * 1024 * 4);
    unsigned short* hb0    = (unsigned short*)alloc(3584ull * 1024 * 2);
    unsigned short* hb1    = (unsigned short*)alloc(3584ull * 1024 * 2);
    unsigned short* hfinal = (unsigned short*)alloc(3584ull * 1024 * 2);

    const size_t SF = 256 * 1024;

    // 1) conversions
    transpose_bt<<<14336, 256, 0, stream>>>(inputs, xt);
    f32_to_bf16<<<16384, 256, 0, stream>>>(roll_Wih, rWih, 4194304, 4194304);
    f32_to_bf16<<<16384, 256, 0, stream>>>(roll_Whh, rWhh, 4194304, 4194304);
    f32_to_bf16<<<16384, 256, 0, stream>>>(un_Wih, uWih, 4194304, 4194304);
    f32_to_bf16<<<16384, 256, 0, stream>>>(un_Whh, uWhh, 4194304, 4194304);
    f32_to_bf16<<<10240, 256, 0, stream>>>(cls_Wf, cWp, 2573312, 2621440);
    bias_interleave<<<16, 256, 0, stream>>>(roll_bih, roll_bhh, rbias4, 4096);
    bias_interleave<<<16, 256, 0, stream>>>(un_bih, un_bhh, ubias4, 4096);

    // 2) unroll input projection -> Xpre (gate-interleaved, +bias)
    lstm_fused<128, 0><<<dim3(32, 28), 256, 0, stream>>>(
        xt, uWih, 16, nullptr, nullptr, 0,
        nullptr, ubias4, nullptr, nullptr, nullptr, nullptr, -1,
        Xpre, nullptr, nullptr);

    // 3) rolling LSTM, fully fused (state lands branch-major in hb0/uc)
    for (int t = 0; t < 14; ++t) {
        const unsigned short* hprev = (t == 0) ? xt : hb0 + (size_t)(t - 1) * SF;
        const float* cprev = (t == 0) ? nullptr : uc + (size_t)(t - 1) * SF;
        lstm_fused<64, 1><<<dim3(32, 4), 256, 0, stream>>>(
            xt + (size_t)t * SF, rWih, 16, hprev, rWhh, (t == 0) ? 0 : 16,
            nullptr, rbias4, cprev, uc + (size_t)t * SF,
            hb0 + (size_t)t * SF, nullptr, -1, nullptr, nullptr, nullptr);
    }

    // 4) unrolling LSTM, fused; h ping-pongs, retiring branch writes hfinal
    for (int s = 0; s <= 14; ++s) {
        int nb = (15 - s < 14) ? (15 - s) : 14;
        int M = nb * 256;
        const unsigned short* hsrc = (s & 1) ? hb1 : hb0;
        unsigned short* hdst = (s & 1) ? hb0 : hb1;
        lstm_fused<128, 1><<<dim3(32, M / 128), 256, 0, stream>>>(
            hsrc, uWhh, 16, nullptr, nullptr, 0,
            Xpre, nullptr, uc, uc, hdst, hfinal, (s >= 1) ? (14 - s) : -1,
            nullptr, nullptr, nullptr);
    }

    // 5) classifier from hfinal
    lstm_fused<128, 2><<<dim3(20, 28), 256, 0, stream>>>(
        hfinal, cWp, 16, nullptr, nullptr, 0,
        nullptr, nullptr, nullptr, nullptr, nullptr, nullptr, -1,
        nullptr, cls_b, out);
}

// Round 4
// 894.428 us; speedup vs baseline: 1.2652x; 1.2652x over previous
//
#include <hip/hip_runtime.h>

#define DEVFN __device__ __forceinline__

typedef __bf16 bf16x8 __attribute__((ext_vector_type(8)));
typedef float floatx4 __attribute__((ext_vector_type(4)));
typedef unsigned short us4 __attribute__((ext_vector_type(4)));

// ---------- helpers ----------

DEVFN unsigned short f2bf(float x) {
    union { float f; unsigned u; } v; v.f = x;
    v.u += 0x7FFFu + ((v.u >> 16) & 1u);   // RNE
    return (unsigned short)(v.u >> 16);
}

DEVFN float bf2f(unsigned short s) {
    union { unsigned u; float f; } v; v.u = ((unsigned)s) << 16; return v.f;
}

DEVFN float sigm(float x) { return 1.f / (1.f + __expf(-x)); }
DEVFN float tanh_fast(float x) { float t = __expf(2.f * x); return 1.f - 2.f / (t + 1.f); }

DEVFN void gload_lds16(const unsigned short* g, unsigned short* l) {
    __builtin_amdgcn_global_load_lds(
        (__attribute__((address_space(1))) unsigned int*)g,
        (__attribute__((address_space(3))) unsigned int*)l, 16, 0, 0);
}

// ---------- conversion kernels ----------

// inputs [256,14,1024] f32 -> xt [14,256,1024] bf16  (x4 vectorized)
__global__ __launch_bounds__(256) void transpose_bt(const float* __restrict__ in,
                                                    unsigned short* __restrict__ out) {
    int idx = blockIdx.x * 256 + threadIdx.x;          // one float4 each
    int k4 = (idx & 255) << 2;
    int row = idx >> 8;                                // t*256 + b
    int t = row >> 8, b = row & 255;
    float4 v = *(const float4*)(in + (size_t)(b * 14 + t) * 1024 + k4);
    us4 o = {f2bf(v.x), f2bf(v.y), f2bf(v.z), f2bf(v.w)};
    *(us4*)(out + (size_t)row * 1024 + k4) = o;
}

// all four LSTM weight matrices (each 4*1024*1024 = 2^22 elems), x4 vectorized
__global__ __launch_bounds__(256) void conv_w4(const float* __restrict__ s0, const float* __restrict__ s1,
                                               const float* __restrict__ s2, const float* __restrict__ s3,
                                               unsigned short* __restrict__ d0, unsigned short* __restrict__ d1,
                                               unsigned short* __restrict__ d2, unsigned short* __restrict__ d3) {
    int t = blockIdx.x * 256 + threadIdx.x;            // 0..2^22-1, 4 elems each
    int which = t >> 20;
    int off = (t & 1048575) << 2;
    const float* s = (which == 0) ? s0 : (which == 1) ? s1 : (which == 2) ? s2 : s3;
    unsigned short* d = (which == 0) ? d0 : (which == 1) ? d1 : (which == 2) ? d2 : d3;
    float4 v = *(const float4*)(s + off);
    us4 o = {f2bf(v.x), f2bf(v.y), f2bf(v.z), f2bf(v.w)};
    *(us4*)(d + off) = o;
}

// cls_W [2513*1024] -> padded [2560*1024] bf16, x4 vectorized
__global__ __launch_bounds__(256) void conv_cls(const float* __restrict__ in,
                                                unsigned short* __restrict__ out) {
    int t = blockIdx.x * 256 + threadIdx.x;            // 0..655359
    int off = t << 2;
    us4 o = {0, 0, 0, 0};
    if (off < 2573312) {
        float4 v = *(const float4*)(in + off);
        o = (us4){f2bf(v.x), f2bf(v.y), f2bf(v.z), f2bf(v.w)};
    }
    *(us4*)(out + off) = o;
}

// bias (gate-major [4][1024]) -> gate-interleaved float4 [1024][4]
__global__ __launch_bounds__(256) void bias_interleave(const float* __restrict__ a,
                                                       const float* __restrict__ b,
                                                       float* __restrict__ o4, int n) {
    int i = blockIdx.x * 256 + threadIdx.x;
    if (i < n) {
        int g = i >> 10, h = i & 1023;
        o4[h * 4 + g] = a[i] + b[i];
    }
}

// roll t=0: gates = Xroll only, c_prev = 0, h_prev = 0
__global__ __launch_bounds__(256) void cell_only(const float* __restrict__ pre4,
                                                 float* __restrict__ c_out,
                                                 unsigned short* __restrict__ h_out) {
    int idx = blockIdx.x * 256 + threadIdx.x;          // (m,h) over 256*1024
    float4 g = ((const float4*)pre4)[idx];
    float iv = sigm(g.x), fv = sigm(g.y);
    float gv = tanh_fast(g.z), ov = sigm(g.w);
    float cn = iv * gv;                                // f*0 + i*g
    float hn = ov * tanh_fast(cn);
    c_out[idx] = cn;
    h_out[idx] = f2bf(hn);
}

// ---------- fused LSTM GEMM ----------
// out[m,n] = sum_k A[m,k]*W[n,k], K = 1024 fixed (BK=64, 16 k-tiles).
// MODE 0: gates f32 store -> gout_f[(m*1024+h)*4+{i,f,g,o}] = acc + bias4
// MODE 3: gates bf16 store -> gout_bf, same layout
// MODE 1: fused LSTM cell -> c_out f32, h bf16; pre4 (f32 or bf16 per PREBF) added
// MODE 2: classifier -> outp[(b*14+t)*2513+n] = acc + clsb[n]   (m = t*256+b)
//
// B-tile (MODE 0/1/3): 128 LDS rows = 4 gates x 32 h gathered so a thread's
// j-frags are gates i,f,g,o at one (m,h).
// LDS k-chunks XOR-swizzled via pre-swizzled GLOBAL source (rule 21).
// 1D grid + XCD-chunked block swizzle (nwg % 8 == 0 for every launch).
template <int BM, int MODE, int PREBF>
__global__ __launch_bounds__(256)
void lstm_fused(const unsigned short* __restrict__ A1, const unsigned short* __restrict__ W1,
                const void* __restrict__ pre4,
                const float* __restrict__ bias4,
                const float* __restrict__ c_in,
                float* __restrict__ c_out,
                unsigned short* __restrict__ h_out,
                unsigned short* __restrict__ h_alt, int retire_t,
                float* __restrict__ gout_f,
                unsigned short* __restrict__ gout_bf,
                const float* __restrict__ clsb,
                float* __restrict__ outp, int gx) {
    constexpr int BK = 64;
    constexpr int KT = 16;                      // 1024 / BK
    constexpr int FM = BM / 32;
    constexpr int AISS = (BM * BK * 2) / 4096;
    constexpr int BISS = (128 * BK * 2) / 4096;

    __shared__ unsigned short ldsA[BM * BK];
    __shared__ unsigned short ldsB[128 * BK];

    const int tid = threadIdx.x;
    const int nwg = gridDim.x;
    int id = blockIdx.x;
    id = ((id & 7) * (nwg >> 3)) + (id >> 3);   // XCD-chunked swizzle
    const int bx = id % gx;
    const int by = id / gx;
    const int m0 = by * BM;
    const int n0 = bx * ((MODE == 2) ? 128 : 32);
    const int lane = tid & 63;
    const int wv = tid >> 6;
    const int wm = wv >> 1, wn = wv & 1;
    const int r16 = lane & 15;
    const int kg = lane >> 4;

    floatx4 acc[FM][4];
#pragma unroll
    for (int i = 0; i < FM; ++i)
#pragma unroll
        for (int j = 0; j < 4; ++j) acc[i][j] = {0.f, 0.f, 0.f, 0.f};

    for (int kt = 0; kt < KT; ++kt) {
        const int ko = kt * BK;
#pragma unroll
        for (int is = 0; is < AISS; ++is) {
            int c = is * 256 + tid;
            int row = c >> 3, kq = c & 7;
            int kqg = kq ^ (row & 7);           // pre-swizzled source chunk
            gload_lds16(A1 + (size_t)(m0 + row) * 1024 + ko + kqg * 8, &ldsA[c * 8]);
        }
#pragma unroll
        for (int is = 0; is < BISS; ++is) {
            int c = is * 256 + tid;
            int row = c >> 3, kq = c & 7;
            int kqg = kq ^ (row & 7);
            int wr;
            if (MODE == 2) wr = n0 + row;
            else wr = ((row >> 4) & 3) * 1024 + n0 + ((row >> 6) << 4) + (row & 15);
            gload_lds16(W1 + (size_t)wr * 1024 + ko + kqg * 8, &ldsB[c * 8]);
        }
        __syncthreads();

#pragma unroll
        for (int kk = 0; kk < 2; ++kk) {
            bf16x8 a[FM], b[4];
            const int kqg = kk * 4 + kg;
#pragma unroll
            for (int i = 0; i < FM; ++i) {
                int row = wm * (BM / 2) + i * 16 + r16;
                a[i] = *(const bf16x8*)&ldsA[row * BK + (kqg ^ (row & 7)) * 8];
            }
#pragma unroll
            for (int j = 0; j < 4; ++j) {
                int row = wn * 64 + j * 16 + r16;
                b[j] = *(const bf16x8*)&ldsB[row * BK + (kqg ^ (row & 7)) * 8];
            }
#pragma unroll
            for (int i = 0; i < FM; ++i)
#pragma unroll
                for (int j = 0; j < 4; ++j)
                    acc[i][j] = __builtin_amdgcn_mfma_f32_16x16x32_bf16(a[i], b[j], acc[i][j], 0, 0, 0);
        }
        __syncthreads();
    }

    // ---------- epilogue ----------
    if (MODE == 2) {
#pragma unroll
        for (int i = 0; i < FM; ++i)
#pragma unroll
            for (int j = 0; j < 4; ++j)
#pragma unroll
                for (int rg = 0; rg < 4; ++rg) {
                    int m = m0 + wm * (BM / 2) + i * 16 + kg * 4 + rg;
                    int gn = n0 + wn * 64 + j * 16 + r16;
                    if (gn < 2513) {
                        int bb = m & 255, tt = m >> 8;
                        outp[(size_t)(bb * 14 + tt) * 2513 + gn] = acc[i][j][rg] + clsb[gn];
                    }
                }
        return;
    }

    const int h = n0 + wn * 16 + r16;
    float4 bv = make_float4(0.f, 0.f, 0.f, 0.f);
    if (bias4) bv = *(const float4*)(bias4 + (size_t)h * 4);
    unsigned short* hw = h_out;
    if (MODE == 1 && (m0 >> 8) == retire_t) hw = h_alt;

#pragma unroll
    for (int i = 0; i < FM; ++i)
#pragma unroll
        for (int rg = 0; rg < 4; ++rg) {
            int m = m0 + wm * (BM / 2) + i * 16 + kg * 4 + rg;
            size_t mh = (size_t)m * 1024 + h;
            float gi_ = acc[i][0][rg] + bv.x;
            float gf_ = acc[i][1][rg] + bv.y;
            float gg_ = acc[i][2][rg] + bv.z;
            float go_ = acc[i][3][rg] + bv.w;
            if (MODE == 0) {
                *(float4*)(gout_f + mh * 4) = make_float4(gi_, gf_, gg_, go_);
            } else if (MODE == 3) {
                us4 o = {f2bf(gi_), f2bf(gf_), f2bf(gg_), f2bf(go_)};
                *(us4*)(gout_bf + mh * 4) = o;
            } else {
                if (pre4) {
                    if (PREBF) {
                        us4 pv = *(const us4*)((const unsigned short*)pre4 + mh * 4);
                        gi_ += bf2f(pv.x); gf_ += bf2f(pv.y);
                        gg_ += bf2f(pv.z); go_ += bf2f(pv.w);
                    } else {
                        float4 pv = ((const float4*)pre4)[mh];
                        gi_ += pv.x; gf_ += pv.y; gg_ += pv.z; go_ += pv.w;
                    }
                }
                float co = c_in ? c_in[mh] : 0.f;
                float iv = sigm(gi_), fv = sigm(gf_);
                float gv = tanh_fast(gg_), ov = sigm(go_);
                float cn = fv * co + iv * gv;
                float hn = ov * tanh_fast(cn);
                c_out[mh] = cn;
                hw[mh] = f2bf(hn);
            }
        }
}

// ---------- launch ----------

extern "C" void kernel_launch(void* const* d_in, const int* in_sizes, int n_in,
                              void* d_out, int out_size, void* d_ws, size_t ws_size,
                              hipStream_t stream) {
    (void)in_sizes; (void)n_in; (void)out_size; (void)ws_size;
    const float* inputs   = (const float*)d_in[0];
    const float* roll_Wih = (const float*)d_in[1];
    const float* roll_Whh = (const float*)d_in[2];
    const float* roll_bih = (const float*)d_in[3];
    const float* roll_bhh = (const float*)d_in[4];
    const float* un_Wih   = (const float*)d_in[5];
    const float* un_Whh   = (const float*)d_in[6];
    const float* un_bih   = (const float*)d_in[7];
    const float* un_bhh   = (const float*)d_in[8];
    const float* cls_Wf   = (const float*)d_in[9];
    const float* cls_b    = (const float*)d_in[10];
    float* out = (float*)d_out;

    char* ws = (char*)d_ws;
    size_t off = 0;
    auto alloc = [&](size_t bytes) -> char* {
        char* p = ws + off;
        off += (bytes + 255) & ~(size_t)255;
        return p;
    };
    unsigned short* xt   = (unsigned short*)alloc(3584ull * 1024 * 2);
    unsigned short* rWih = (unsigned short*)alloc(4096ull * 1024 * 2);
    unsigned short* rWhh = (unsigned short*)alloc(4096ull * 1024 * 2);
    unsigned short* uWih = (unsigned short*)alloc(4096ull * 1024 * 2);
    unsigned short* uWhh = (unsigned short*)alloc(4096ull * 1024 * 2);
    unsigned short* cWp  = (unsigned short*)alloc(2560ull * 1024 * 2);
    float* rbias4 = (float*)alloc(1024 * 4 * 4);
    float* ubias4 = (float*)alloc(1024 * 4 * 4);
    unsigned short* XpreB = (unsigned short*)alloc(3584ull * 4096 * 2);  // unroll x-proj, bf16 [m][h][4]
    float* Xroll  = (float*)alloc(3584ull * 4096 * 4);                   // roll x-proj, f32 [m][h][4]
    float* uc     = (float*)alloc(3584ull * 1024 * 4);
    unsigned short* hb0    = (unsigned short*)alloc(3584ull * 1024 * 2);
    unsigned short* hb1    = (unsigned short*)alloc(3584ull * 1024 * 2);
    unsigned short* hfinal = (unsigned short*)alloc(3584ull * 1024 * 2);

    const size_t SF = 256 * 1024;

    // 1) conversions
    transpose_bt<<<3584, 256, 0, stream>>>(inputs, xt);
    conv_w4<<<16384, 256, 0, stream>>>(roll_Wih, roll_Whh, un_Wih, un_Whh,
                                       rWih, rWhh, uWih, uWhh);
    conv_cls<<<2560, 256, 0, stream>>>(cls_Wf, cWp);
    bias_interleave<<<16, 256, 0, stream>>>(roll_bih, roll_bhh, rbias4, 4096);
    bias_interleave<<<16, 256, 0, stream>>>(un_bih, un_bhh, ubias4, 4096);

    // 2) x-projections (hoisted out of both scans)
    lstm_fused<128, 3, 0><<<896, 256, 0, stream>>>(
        xt, uWih, nullptr, ubias4, nullptr, nullptr, nullptr, nullptr, -1,
        nullptr, XpreB, nullptr, nullptr, 32);
    lstm_fused<128, 0, 0><<<896, 256, 0, stream>>>(
        xt, rWih, nullptr, rbias4, nullptr, nullptr, nullptr, nullptr, -1,
        Xroll, nullptr, nullptr, nullptr, 32);

    // 3) rolling LSTM: t=0 elementwise, t>=1 h-only GEMM (K=1024) + fused cell
    cell_only<<<1024, 256, 0, stream>>>(Xroll, uc, hb0);
    for (int t = 1; t < 14; ++t) {
        lstm_fused<32, 1, 0><<<256, 256, 0, stream>>>(
            hb0 + (size_t)(t - 1) * SF, rWhh,
            Xroll + (size_t)t * SF * 4, nullptr,
            uc + (size_t)(t - 1) * SF, uc + (size_t)t * SF,
            hb0 + (size_t)t * SF, nullptr, -1,
            nullptr, nullptr, nullptr, nullptr, 32);
    }

    // 4) unrolling LSTM: fused, shrinking prefix; retiring branch -> hfinal
    for (int s = 0; s <= 14; ++s) {
        int nb = (15 - s < 14) ? (15 - s) : 14;
        int M = nb * 256;
        const unsigned short* hsrc = (s & 1) ? hb1 : hb0;
        unsigned short* hdst = (s & 1) ? hb0 : hb1;
        int rt = (s >= 1) ? (14 - s) : -1;
        if (M >= 2048) {
            lstm_fused<128, 1, 1><<<32 * (M / 128), 256, 0, stream>>>(
                hsrc, uWhh, XpreB, nullptr, uc, uc, hdst, hfinal, rt,
                nullptr, nullptr, nullptr, nullptr, 32);
        } else if (M >= 1024) {
            lstm_fused<64, 1, 1><<<32 * (M / 64), 256, 0, stream>>>(
                hsrc, uWhh, XpreB, nullptr, uc, uc, hdst, hfinal, rt,
                nullptr, nullptr, nullptr, nullptr, 32);
        } else {
            lstm_fused<32, 1, 1><<<32 * (M / 32), 256, 0, stream>>>(
                hsrc, uWhh, XpreB, nullptr, uc, uc, hdst, hfinal, rt,
                nullptr, nullptr, nullptr, nullptr, 32);
        }
    }

    // 5) classifier from hfinal
    lstm_fused<128, 2, 0><<<560, 256, 0, stream>>>(
        hfinal, cWp, nullptr, nullptr, nullptr, nullptr, nullptr, nullptr, -1,
        nullptr, nullptr, cls_b, out, 20);
}